// Round 1
// baseline (618.322 us; speedup 1.0000x reference)
//
#include <hip/hip_runtime.h>

// Fused attention block: x @ Wqkv -> flash attention -> @ Wout + b -> LayerNorm
// B=4, N=2048, DIM=1024, HEADS=16, HEAD_DIM=64. All fp32 in/out; bf16 MFMA inside.
//
// Workspace layout (needs ~84 MB):
//   qkv  : bf16 [8192][3072]  (Q cols 0..1023 pre-scaled by 1/8)
//   aout : bf16 [8192][1024]
//   proj : bf16 [8192][1024]

typedef __bf16 bf16;
typedef __bf16 bf16x4 __attribute__((ext_vector_type(4)));
typedef __bf16 bf16x8 __attribute__((ext_vector_type(8)));
typedef float f32x4 __attribute__((ext_vector_type(4)));
typedef unsigned int u32x4 __attribute__((ext_vector_type(4)));

#define K_DIM 1024

__device__ __forceinline__ unsigned pack2(float lo, float hi) {
  union { __bf16 b; unsigned short u; } a, c;
  a.b = (__bf16)lo; c.b = (__bf16)hi;
  return (unsigned)a.u | ((unsigned)c.u << 16);
}

// C[M][Ncols] = A[M][1024] @ B[1024][Ncols], A fp32 or bf16, B fp32 (convert on stage).
// 128x128 tile, BK=32, 4 waves (2x2), each wave 64x64 = 4x4 frags of 16x16x32 MFMA.
template <int LDB, bool A_BF16, bool QSCALE>
__global__ __launch_bounds__(256) void gemm_k(const void* __restrict__ Ap,
                                              const float* __restrict__ Bp,
                                              bf16* __restrict__ Cp, int Ncols) {
  __shared__ bf16 As[128][40];   // [m][k], pad 32->40 (16B-aligned rows, 2-way banks)
  __shared__ bf16 Bs[128][40];   // transposed: [n][k]
  const int tid = threadIdx.x;
  const int l = tid & 63, w = tid >> 6;
  const int g = l >> 4, q = l & 15;
  const int wm = w >> 1, wn = w & 1;
  const int m0 = blockIdx.x * 128, n0 = blockIdx.y * 128;

  f32x4 acc[4][4] = {};

  for (int k0 = 0; k0 < K_DIM; k0 += 32) {
    __syncthreads();
    if (A_BF16) {
      const bf16* A = (const bf16*)Ap;
#pragma unroll
      for (int o = tid; o < 512; o += 256) {        // 512 octs of 8 bf16
        const int row = o >> 2, oc = o & 3;
        bf16x8 v = *(const bf16x8*)(A + (size_t)(m0 + row) * K_DIM + k0 + oc * 8);
        *(bf16x8*)&As[row][oc * 8] = v;
      }
    } else {
      const float* A = (const float*)Ap;
#pragma unroll
      for (int o = tid; o < 1024; o += 256) {       // 1024 quads of 4 f32
        const int row = o >> 3, qc = o & 7;
        float4 v = *(const float4*)(A + (size_t)(m0 + row) * K_DIM + k0 + qc * 4);
        bf16x4 bb = {(bf16)v.x, (bf16)v.y, (bf16)v.z, (bf16)v.w};
        *(bf16x4*)&As[row][qc * 4] = bb;
      }
    }
    // B tile [32][128] -> transposed scatter into Bs[n][k]
#pragma unroll
    for (int o = tid; o < 1024; o += 256) {
      const int kk = o >> 5, j4 = o & 31;
      float4 v = *(const float4*)(Bp + (size_t)(k0 + kk) * LDB + n0 + j4 * 4);
      Bs[j4 * 4 + 0][kk] = (bf16)v.x;
      Bs[j4 * 4 + 1][kk] = (bf16)v.y;
      Bs[j4 * 4 + 2][kk] = (bf16)v.z;
      Bs[j4 * 4 + 3][kk] = (bf16)v.w;
    }
    __syncthreads();

    bf16x8 af[4], bfr[4];
#pragma unroll
    for (int mi = 0; mi < 4; mi++)
      af[mi] = *(const bf16x8*)&As[wm * 64 + mi * 16 + q][g * 8];
#pragma unroll
    for (int ni = 0; ni < 4; ni++)
      bfr[ni] = *(const bf16x8*)&Bs[wn * 64 + ni * 16 + q][g * 8];
#pragma unroll
    for (int mi = 0; mi < 4; mi++)
#pragma unroll
      for (int ni = 0; ni < 4; ni++)
        acc[mi][ni] = __builtin_amdgcn_mfma_f32_16x16x32_bf16(af[mi], bfr[ni], acc[mi][ni], 0, 0, 0);
  }

#pragma unroll
  for (int mi = 0; mi < 4; mi++)
#pragma unroll
    for (int ni = 0; ni < 4; ni++) {
      const int col = n0 + wn * 64 + ni * 16 + q;
      const float s = (QSCALE && col < 1024) ? 0.125f : 1.0f;  // Q * head_dim^-0.5
#pragma unroll
      for (int r = 0; r < 4; r++) {
        const int row = m0 + wm * 64 + mi * 16 + g * 4 + r;
        Cp[(size_t)row * Ncols + col] = (bf16)(acc[mi][ni][r] * s);
      }
    }
}

// Flash attention. Grid (32 qtiles, 16 heads, 4 batch), 256 thr = 4 waves.
// Each wave owns 16 q-rows. KV tile = 32. Swapped S^T = mfma(K, Q) so the
// softmax row (fixed q over kv) needs only in-lane reduce + shfl_xor(16/32).
__global__ __launch_bounds__(256) void attn_k(const bf16* __restrict__ qkv,
                                              bf16* __restrict__ aout) {
  __shared__ bf16 Vt[64][40];   // V^T tile: [d][kv], pad 32->40
  const int tid = threadIdx.x;
  const int l = tid & 63, w = tid >> 6;
  const int g = l >> 4, q = l & 15;
  const int h = blockIdx.y, b = blockIdx.z;
  const int q0 = blockIdx.x * 64 + w * 16;
  const size_t base = (size_t)b * 2048 * 3072;

  // Q fragments (B operand of S^T = K·Q^T): lane holds col q, k=d contiguous. Hoisted.
  bf16x8 qf[2];
  {
    const bf16* Qr = qkv + base + (size_t)(q0 + q) * 3072 + h * 64 + g * 8;
    qf[0] = *(const bf16x8*)Qr;
    qf[1] = *(const bf16x8*)(Qr + 32);
  }

  float m = -1e30f, lsum = 0.f;
  f32x4 oacc[4] = {};   // O^T accum: dchunk dc -> rows d = dc*16 + 4g + r, col q

  for (int kt = 0; kt < 2048; kt += 32) {
    __syncthreads();    // previous Vt reads complete
    {                   // stage V[32][64] -> Vt[d][kv], one 16B load + 8 scatter/thread
      const int kv = tid >> 3, d8 = tid & 7;
      bf16x8 v = *(const bf16x8*)(qkv + base + (size_t)(kt + kv) * 3072 + 2048 + h * 64 + d8 * 8);
#pragma unroll
      for (int i = 0; i < 8; i++) Vt[d8 * 8 + i][kv] = v[i];
    }

    // S^T tiles: t=0 -> kv 0..15, t=1 -> kv 16..31. A operand = K rows (direct global).
    f32x4 st[2];
#pragma unroll
    for (int t = 0; t < 2; t++) {
      const bf16* Kr = qkv + base + (size_t)(kt + t * 16 + q) * 3072 + 1024 + h * 64 + g * 8;
      bf16x8 kf0 = *(const bf16x8*)Kr;
      bf16x8 kf1 = *(const bf16x8*)(Kr + 32);
      f32x4 z = {0.f, 0.f, 0.f, 0.f};
      z = __builtin_amdgcn_mfma_f32_16x16x32_bf16(kf0, qf[0], z, 0, 0, 0);
      st[t] = __builtin_amdgcn_mfma_f32_16x16x32_bf16(kf1, qf[1], z, 0, 0, 0);
    }

    // Online softmax. Lane holds 8 scores of row q (kv = 16t + 4g + r).
    float tmax = st[0][0];
#pragma unroll
    for (int t = 0; t < 2; t++)
#pragma unroll
      for (int r = 0; r < 4; r++) tmax = fmaxf(tmax, st[t][r]);
    tmax = fmaxf(tmax, __shfl_xor(tmax, 16));
    tmax = fmaxf(tmax, __shfl_xor(tmax, 32));
    const float mnew = fmaxf(m, tmax);
    const float corr = __expf(m - mnew);
    float p[2][4];
    float tsum = 0.f;
#pragma unroll
    for (int t = 0; t < 2; t++)
#pragma unroll
      for (int r = 0; r < 4; r++) { p[t][r] = __expf(st[t][r] - mnew); tsum += p[t][r]; }
    tsum += __shfl_xor(tsum, 16);
    tsum += __shfl_xor(tsum, 32);
    lsum = lsum * corr + tsum;
    m = mnew;
#pragma unroll
    for (int dc = 0; dc < 4; dc++)
#pragma unroll
      for (int r = 0; r < 4; r++) oacc[dc][r] *= corr;

    // Redistribute P^T into the PV B-fragment (lane wants kv = 8g..8g+7 at col q).
    unsigned pk0[2], pk1[2];
    pk0[0] = pack2(p[0][0], p[0][1]); pk0[1] = pack2(p[0][2], p[0][3]);
    pk1[0] = pack2(p[1][0], p[1][1]); pk1[1] = pack2(p[1][2], p[1][3]);
    u32x4 bw;
#pragma unroll
    for (int wd = 0; wd < 4; wd++) {
      const int src = q + 16 * ((g & 1) * 2 + (wd >> 1));
      const unsigned lo = (unsigned)__shfl((int)pk0[wd & 1], src);
      const unsigned hi = (unsigned)__shfl((int)pk1[wd & 1], src);
      bw[wd] = (g < 2) ? lo : hi;   // tile = g>>1
    }
    const bf16x8 pfrag = __builtin_bit_cast(bf16x8, bw);

    __syncthreads();    // Vt staged
#pragma unroll
    for (int dc = 0; dc < 4; dc++) {
      bf16x8 vf = *(const bf16x8*)&Vt[dc * 16 + q][g * 8];   // V^T A-frag
      oacc[dc] = __builtin_amdgcn_mfma_f32_16x16x32_bf16(vf, pfrag, oacc[dc], 0, 0, 0);
    }
  }

  const float inv = 1.f / lsum;
  bf16* orow = aout + (size_t)(b * 2048 + q0 + q) * 1024 + h * 64;
#pragma unroll
  for (int dc = 0; dc < 4; dc++) {
    bf16x4 o = {(bf16)(oacc[dc][0] * inv), (bf16)(oacc[dc][1] * inv),
                (bf16)(oacc[dc][2] * inv), (bf16)(oacc[dc][3] * inv)};
    *(bf16x4*)(orow + dc * 16 + g * 4) = o;   // d = dc*16 + 4g + r
  }
}

// Bias + LayerNorm epilogue: one block per row of proj[8192][1024].
__global__ __launch_bounds__(256) void ln_k(const bf16* __restrict__ proj,
                                            const float* __restrict__ bo,
                                            const float* __restrict__ gam,
                                            const float* __restrict__ bet,
                                            float* __restrict__ out) {
  const int row = blockIdx.x, tid = threadIdx.x;
  const int l = tid & 63, w = tid >> 6;
  bf16x4 pv = *(const bf16x4*)(proj + (size_t)row * 1024 + tid * 4);
  float4 bv = *(const float4*)(bo + tid * 4);
  float v0 = (float)pv[0] + bv.x, v1 = (float)pv[1] + bv.y;
  float v2 = (float)pv[2] + bv.z, v3 = (float)pv[3] + bv.w;
  float s = v0 + v1 + v2 + v3;
  float ss = v0 * v0 + v1 * v1 + v2 * v2 + v3 * v3;
#pragma unroll
  for (int off = 32; off > 0; off >>= 1) {
    s += __shfl_xor(s, off);
    ss += __shfl_xor(ss, off);
  }
  __shared__ float red[8];
  if (l == 0) { red[w] = s; red[w + 4] = ss; }
  __syncthreads();
  const float S = red[0] + red[1] + red[2] + red[3];
  const float SS = red[4] + red[5] + red[6] + red[7];
  const float mean = S * (1.f / 1024.f);
  const float var = SS * (1.f / 1024.f) - mean * mean;
  const float rs = rsqrtf(var + 1e-5f);
  float4 gv = *(const float4*)(gam + tid * 4);
  float4 btv = *(const float4*)(bet + tid * 4);
  float4 o;
  o.x = (v0 - mean) * rs * gv.x + btv.x;
  o.y = (v1 - mean) * rs * gv.y + btv.y;
  o.z = (v2 - mean) * rs * gv.z + btv.z;
  o.w = (v3 - mean) * rs * gv.w + btv.w;
  *(float4*)(out + (size_t)row * 1024 + tid * 4) = o;
}

extern "C" void kernel_launch(void* const* d_in, const int* in_sizes, int n_in,
                              void* d_out, int out_size, void* d_ws, size_t ws_size,
                              hipStream_t stream) {
  const float* x      = (const float*)d_in[0];
  const float* w_qkv  = (const float*)d_in[1];
  const float* w_out  = (const float*)d_in[2];
  const float* b_out  = (const float*)d_in[3];
  const float* gamma  = (const float*)d_in[4];
  const float* beta   = (const float*)d_in[5];
  float* out = (float*)d_out;

  char* ws = (char*)d_ws;
  bf16* qkv  = (bf16*)ws;                          // 8192*3072*2 = 50331648 B
  bf16* aout = (bf16*)(ws + 50331648);             // 8192*1024*2 = 16777216 B
  bf16* proj = (bf16*)(ws + 67108864);             // 8192*1024*2 = 16777216 B

  dim3 blk(256);
  gemm_k<3072, false, true><<<dim3(64, 24), blk, 0, stream>>>(x, w_qkv, qkv, 3072);
  attn_k<<<dim3(32, 16, 4), blk, 0, stream>>>(qkv, aout);
  gemm_k<1024, true, false><<<dim3(64, 8), blk, 0, stream>>>(aout, w_out, proj, 1024);
  ln_k<<<8192, blk, 0, stream>>>(proj, b_out, gamma, beta, out);
}

// Round 2
// 561.572 us; speedup vs baseline: 1.1011x; 1.1011x over previous
//
#include <hip/hip_runtime.h>

// Fused attention block: x @ Wqkv -> flash attention -> @ Wout + b -> LayerNorm
// B=4, N=2048, DIM=1024, HEADS=16, HEAD_DIM=64. fp32 in/out; bf16 MFMA inside.
//
// Workspace (75.5 MB):
//   xbf   bf16 [8192][1024]   (x converted; later reused as aout)
//   wqkvT bf16 [3072][1024]   (w_qkv^T)
//   woutT bf16 [1024][1024]   (w_out^T)
//   qk    bf16 [8192][2048]   (Q cols 0..1023 pre-scaled by 0.125*log2e, K cols 1024..2047)
//   vt    bf16 [4][16][64][2048] (V^T per (b,h); later reused as proj)

typedef __bf16 bf16;
typedef __bf16 bf16x4 __attribute__((ext_vector_type(4)));
typedef __bf16 bf16x8 __attribute__((ext_vector_type(8)));
typedef float f32x4 __attribute__((ext_vector_type(4)));
typedef unsigned int u32x4 __attribute__((ext_vector_type(4)));

#define QSCALE_LOG2E 0.18033688011112042f  // 0.125 * log2(e)

#define GLOAD_LDS16(gp, lp)                                                   \
  __builtin_amdgcn_global_load_lds(                                           \
      (const __attribute__((address_space(1))) unsigned int*)(const void*)(gp), \
      (__attribute__((address_space(3))) unsigned int*)(void*)(lp), 16, 0, 0)

__device__ __forceinline__ unsigned pack2(float lo, float hi) {
  union { __bf16 b; unsigned short u; } a, c;
  a.b = (__bf16)lo; c.b = (__bf16)hi;
  return (unsigned)a.u | ((unsigned)c.u << 16);
}

// fp32 -> bf16 bulk convert (x). 8 elems/thread.
__global__ __launch_bounds__(256) void cvt_k(const float* __restrict__ in,
                                             bf16* __restrict__ out) {
  const size_t i = ((size_t)blockIdx.x * 256 + threadIdx.x) * 8;
  float4 a = *(const float4*)(in + i);
  float4 b = *(const float4*)(in + i + 4);
  bf16x8 o = {(bf16)a.x, (bf16)a.y, (bf16)a.z, (bf16)a.w,
              (bf16)b.x, (bf16)b.y, (bf16)b.z, (bf16)b.w};
  *(bf16x8*)(out + i) = o;
}

// in fp32 [Kd][Nd] -> out bf16 [Nd][Kd] (transposed). 32x32 tiles.
__global__ __launch_bounds__(256) void transpose_k(const float* __restrict__ in,
                                                   bf16* __restrict__ out,
                                                   int Kd, int Nd) {
  __shared__ bf16 t[32][36];
  const int n0 = blockIdx.x * 32, k0 = blockIdx.y * 32;
  const int r = threadIdx.x >> 3, c4 = (threadIdx.x & 7) * 4;
  float4 v = *(const float4*)(in + (size_t)(k0 + r) * Nd + n0 + c4);
  t[c4 + 0][r] = (bf16)v.x; t[c4 + 1][r] = (bf16)v.y;
  t[c4 + 2][r] = (bf16)v.z; t[c4 + 3][r] = (bf16)v.w;
  __syncthreads();
  bf16x4 o = *(const bf16x4*)&t[r][c4];
  *(bf16x4*)(out + (size_t)(n0 + r) * Kd + k0 + c4) = o;
}

// C[M][N] = A[M][1024] @ Bt[N][1024]^T, both bf16. 128x128 tile, BK=32,
// global_load_lds width-16, linear LDS (m97 structure).
// QKV epilogue: n0<1024 -> Q (scaled) into qk; <2048 -> K into qk; else V^T into vt.
template <bool QKV>
__global__ __launch_bounds__(256) void gemm2(const bf16* __restrict__ A,
                                             const bf16* __restrict__ Bt,
                                             bf16* __restrict__ C,
                                             bf16* __restrict__ Vt) {
  __shared__ bf16 As[128][32];
  __shared__ bf16 Bs[128][32];
  const int tid = threadIdx.x;
  const int l = tid & 63, w = tid >> 6;
  const int g = l >> 4, q = l & 15;
  const int wm = w >> 1, wn = w & 1;
  const int m0 = blockIdx.x * 128, n0 = blockIdx.y * 128;
  const int lr = l >> 2, lc = (l & 3) * 8;

  f32x4 acc[4][4] = {};

  for (int k0 = 0; k0 < 1024; k0 += 32) {
    __syncthreads();
#pragma unroll
    for (int i = 0; i < 2; i++) {
      const int c = w + i * 4;
      GLOAD_LDS16(A + (size_t)(m0 + c * 16 + lr) * 1024 + k0 + lc, &As[c * 16][0]);
      GLOAD_LDS16(Bt + (size_t)(n0 + c * 16 + lr) * 1024 + k0 + lc, &Bs[c * 16][0]);
    }
    __syncthreads();

    bf16x8 af[4], bfr[4];
#pragma unroll
    for (int mi = 0; mi < 4; mi++)
      af[mi] = *(const bf16x8*)&As[wm * 64 + mi * 16 + q][g * 8];
#pragma unroll
    for (int ni = 0; ni < 4; ni++)
      bfr[ni] = *(const bf16x8*)&Bs[wn * 64 + ni * 16 + q][g * 8];
#pragma unroll
    for (int mi = 0; mi < 4; mi++)
#pragma unroll
      for (int ni = 0; ni < 4; ni++)
        acc[mi][ni] = __builtin_amdgcn_mfma_f32_16x16x32_bf16(af[mi], bfr[ni], acc[mi][ni], 0, 0, 0);
  }

  if (QKV && n0 >= 2048) {
    // V^T: vt[((b*16+h)*64+d)*2048 + n], 4 consecutive tokens per store.
#pragma unroll
    for (int mi = 0; mi < 4; mi++)
#pragma unroll
      for (int ni = 0; ni < 4; ni++) {
        const int vcol = n0 - 2048 + wn * 64 + ni * 16 + q;
        const int h = vcol >> 6, d = vcol & 63;
        const int t0 = m0 + wm * 64 + mi * 16 + g * 4;
        const int b = t0 >> 11, n = t0 & 2047;
        bf16x4 o = {(bf16)acc[mi][ni][0], (bf16)acc[mi][ni][1],
                    (bf16)acc[mi][ni][2], (bf16)acc[mi][ni][3]};
        *(bf16x4*)(Vt + ((size_t)(b * 16 + h) * 64 + d) * 2048 + n) = o;
      }
  } else {
    const int ldc = QKV ? 2048 : 1024;
    const float s = (QKV && n0 < 1024) ? QSCALE_LOG2E : 1.0f;
#pragma unroll
    for (int mi = 0; mi < 4; mi++)
#pragma unroll
      for (int ni = 0; ni < 4; ni++) {
        const int col = n0 + wn * 64 + ni * 16 + q;
#pragma unroll
        for (int r = 0; r < 4; r++) {
          const int row = m0 + wm * 64 + mi * 16 + g * 4 + r;
          C[(size_t)row * ldc + col] = (bf16)(acc[mi][ni][r] * s);
        }
      }
  }
}

// Flash attention, LDS-free. Grid (32 qtiles, 16 h, 4 b), 256 thr = 4 waves.
// Each wave owns 16 q-rows; KVBLK=64. Swapped S^T = mfma(K, Q); scores are in
// log2 units (Q pre-scaled by 0.125*log2e), softmax uses exp2.
__global__ __launch_bounds__(256) void attn_k(const bf16* __restrict__ qk,
                                              const bf16* __restrict__ vt,
                                              bf16* __restrict__ aout) {
  const int tid = threadIdx.x;
  const int l = tid & 63, w = tid >> 6;
  const int g = l >> 4, q = l & 15;
  const int h = blockIdx.y, b = blockIdx.z;
  const int q0 = blockIdx.x * 64 + w * 16;

  // Q fragments (B operand of S^T): lane holds col q, k=d contiguous.
  bf16x8 qf[2];
  {
    const bf16* Qr = qk + (size_t)(b * 2048 + q0 + q) * 2048 + h * 64 + g * 8;
    qf[0] = *(const bf16x8*)Qr;
    qf[1] = *(const bf16x8*)(Qr + 32);
  }
  const bf16* Kbase = qk + (size_t)(b * 2048) * 2048 + 1024 + h * 64 + g * 8;
  const bf16* vrow[4];
#pragma unroll
  for (int dc = 0; dc < 4; dc++)
    vrow[dc] = vt + ((size_t)(b * 16 + h) * 64 + dc * 16 + q) * 2048 + g * 8;

  float m = -1e30f, lsum = 0.f;
  f32x4 oacc[4] = {};  // O^T: dchunk dc -> rows d = dc*16 + 4g + r, col q

  for (int kt = 0; kt < 2048; kt += 64) {
    // S^T tiles: t -> kv 16t..16t+15.
    f32x4 st[4];
#pragma unroll
    for (int t = 0; t < 4; t++) {
      const bf16* Kr = Kbase + (size_t)(kt + t * 16 + q) * 2048;
      bf16x8 kf0 = *(const bf16x8*)Kr;
      bf16x8 kf1 = *(const bf16x8*)(Kr + 32);
      f32x4 z = {0.f, 0.f, 0.f, 0.f};
      z = __builtin_amdgcn_mfma_f32_16x16x32_bf16(kf0, qf[0], z, 0, 0, 0);
      st[t] = __builtin_amdgcn_mfma_f32_16x16x32_bf16(kf1, qf[1], z, 0, 0, 0);
    }
    // Issue V^T fragment loads early (overlap with softmax).
    bf16x8 vf[4][2];
#pragma unroll
    for (int dc = 0; dc < 4; dc++) {
      vf[dc][0] = *(const bf16x8*)(vrow[dc] + kt);
      vf[dc][1] = *(const bf16x8*)(vrow[dc] + kt + 32);
    }

    // Online softmax (log2 domain). Lane holds 16 scores of row q (kv=16t+4g+r).
    float tmax = st[0][0];
#pragma unroll
    for (int t = 0; t < 4; t++)
#pragma unroll
      for (int r = 0; r < 4; r++) tmax = fmaxf(tmax, st[t][r]);
    tmax = fmaxf(tmax, __shfl_xor(tmax, 16));
    tmax = fmaxf(tmax, __shfl_xor(tmax, 32));
    float corr = 1.0f;
    if (__ballot(tmax > m)) {  // defer-max: skip rescale when no row grew (exact)
      const float mnew = fmaxf(m, tmax);
      corr = exp2f(m - mnew);
      m = mnew;
#pragma unroll
      for (int dc = 0; dc < 4; dc++)
#pragma unroll
        for (int r = 0; r < 4; r++) oacc[dc][r] *= corr;
    }
    float p[4][4];
    float tsum = 0.f;
#pragma unroll
    for (int t = 0; t < 4; t++)
#pragma unroll
      for (int r = 0; r < 4; r++) { p[t][r] = exp2f(st[t][r] - m); tsum += p[t][r]; }
    tsum += __shfl_xor(tsum, 16);
    tsum += __shfl_xor(tsum, 32);
    lsum = lsum * corr + tsum;

    // Redistribute P^T into two PV B-fragments (kv 0..31 and 32..63 of this tile).
    unsigned pk[4][2];
#pragma unroll
    for (int t = 0; t < 4; t++) {
      pk[t][0] = pack2(p[t][0], p[t][1]);
      pk[t][1] = pack2(p[t][2], p[t][3]);
    }
    u32x4 bwA, bwB;
#pragma unroll
    for (int wd = 0; wd < 4; wd++) {
      const int src = q + 16 * ((g & 1) * 2 + (wd >> 1));
      const unsigned loA = (unsigned)__shfl((int)pk[0][wd & 1], src);
      const unsigned hiA = (unsigned)__shfl((int)pk[1][wd & 1], src);
      const unsigned loB = (unsigned)__shfl((int)pk[2][wd & 1], src);
      const unsigned hiB = (unsigned)__shfl((int)pk[3][wd & 1], src);
      bwA[wd] = (g < 2) ? loA : hiA;
      bwB[wd] = (g < 2) ? loB : hiB;
    }
    const bf16x8 pfA = __builtin_bit_cast(bf16x8, bwA);
    const bf16x8 pfB = __builtin_bit_cast(bf16x8, bwB);

#pragma unroll
    for (int dc = 0; dc < 4; dc++) {
      oacc[dc] = __builtin_amdgcn_mfma_f32_16x16x32_bf16(vf[dc][0], pfA, oacc[dc], 0, 0, 0);
      oacc[dc] = __builtin_amdgcn_mfma_f32_16x16x32_bf16(vf[dc][1], pfB, oacc[dc], 0, 0, 0);
    }
  }

  const float inv = 1.f / lsum;
  bf16* orow = aout + (size_t)(b * 2048 + q0 + q) * 1024 + h * 64;
#pragma unroll
  for (int dc = 0; dc < 4; dc++) {
    bf16x4 o = {(bf16)(oacc[dc][0] * inv), (bf16)(oacc[dc][1] * inv),
                (bf16)(oacc[dc][2] * inv), (bf16)(oacc[dc][3] * inv)};
    *(bf16x4*)(orow + dc * 16 + g * 4) = o;  // d = dc*16 + 4g + r
  }
}

// Bias + LayerNorm epilogue: one block per row of proj[8192][1024].
__global__ __launch_bounds__(256) void ln_k(const bf16* __restrict__ proj,
                                            const float* __restrict__ bo,
                                            const float* __restrict__ gam,
                                            const float* __restrict__ bet,
                                            float* __restrict__ out) {
  const int row = blockIdx.x, tid = threadIdx.x;
  const int l = tid & 63, w = tid >> 6;
  bf16x4 pv = *(const bf16x4*)(proj + (size_t)row * 1024 + tid * 4);
  float4 bv = *(const float4*)(bo + tid * 4);
  float v0 = (float)pv[0] + bv.x, v1 = (float)pv[1] + bv.y;
  float v2 = (float)pv[2] + bv.z, v3 = (float)pv[3] + bv.w;
  float s = v0 + v1 + v2 + v3;
  float ss = v0 * v0 + v1 * v1 + v2 * v2 + v3 * v3;
#pragma unroll
  for (int off = 32; off > 0; off >>= 1) {
    s += __shfl_xor(s, off);
    ss += __shfl_xor(ss, off);
  }
  __shared__ float red[8];
  if (l == 0) { red[w] = s; red[w + 4] = ss; }
  __syncthreads();
  const float S = red[0] + red[1] + red[2] + red[3];
  const float SS = red[4] + red[5] + red[6] + red[7];
  const float mean = S * (1.f / 1024.f);
  const float var = SS * (1.f / 1024.f) - mean * mean;
  const float rs = rsqrtf(var + 1e-5f);
  float4 gv = *(const float4*)(gam + tid * 4);
  float4 btv = *(const float4*)(bet + tid * 4);
  float4 o;
  o.x = (v0 - mean) * rs * gv.x + btv.x;
  o.y = (v1 - mean) * rs * gv.y + btv.y;
  o.z = (v2 - mean) * rs * gv.z + btv.z;
  o.w = (v3 - mean) * rs * gv.w + btv.w;
  *(float4*)(out + (size_t)row * 1024 + tid * 4) = o;
}

extern "C" void kernel_launch(void* const* d_in, const int* in_sizes, int n_in,
                              void* d_out, int out_size, void* d_ws, size_t ws_size,
                              hipStream_t stream) {
  const float* x      = (const float*)d_in[0];
  const float* w_qkv  = (const float*)d_in[1];
  const float* w_out  = (const float*)d_in[2];
  const float* b_out  = (const float*)d_in[3];
  const float* gamma  = (const float*)d_in[4];
  const float* beta   = (const float*)d_in[5];
  float* out = (float*)d_out;

  char* ws = (char*)d_ws;
  bf16* xbf   = (bf16*)(ws);                      // 16,777,216 B (reused as aout)
  bf16* wqkvT = (bf16*)(ws + 16777216);           //  6,291,456 B
  bf16* woutT = (bf16*)(ws + 23068672);           //  2,097,152 B
  bf16* qkbuf = (bf16*)(ws + 25165824);           // 33,554,432 B
  bf16* vt    = (bf16*)(ws + 58720256);           // 16,777,216 B (reused as proj)
  bf16* aout  = xbf;
  bf16* proj  = vt;

  dim3 blk(256);
  cvt_k<<<4096, blk, 0, stream>>>(x, xbf);
  transpose_k<<<dim3(96, 32), blk, 0, stream>>>(w_qkv, wqkvT, 1024, 3072);
  transpose_k<<<dim3(32, 32), blk, 0, stream>>>(w_out, woutT, 1024, 1024);
  gemm2<true><<<dim3(64, 24), blk, 0, stream>>>(xbf, wqkvT, qkbuf, vt);
  attn_k<<<dim3(32, 16, 4), blk, 0, stream>>>(qkbuf, vt, aout);
  gemm2<false><<<dim3(64, 8), blk, 0, stream>>>(aout, woutT, proj, nullptr);
  ln_k<<<8192, blk, 0, stream>>>(proj, b_out, gamma, beta, out);
}

// Round 3
// 279.349 us; speedup vs baseline: 2.2134x; 2.0103x over previous
//
#include <hip/hip_runtime.h>

// Fused attention block: x @ Wqkv -> flash attention -> @ Wout + b -> LayerNorm
// B=4, N=2048, DIM=1024, HEADS=16, HEAD_DIM=64. fp32 in/out; bf16 MFMA inside.
//
// Workspace (75.5 MB):
//   xbf   bf16 [8192][1024]   (x converted; later reused as aout)
//   wqkvT bf16 [3072][1024]   (w_qkv^T)
//   woutT bf16 [1024][1024]   (w_out^T)
//   qk    bf16 [8192][2048]   (Q cols 0..1023 pre-scaled by 0.125*log2e, K cols 1024..2047)
//   vt    bf16 [4][16][64][2048] (V^T per (b,h); later reused as proj)

typedef __bf16 bf16;
typedef __bf16 bf16x4 __attribute__((ext_vector_type(4)));
typedef __bf16 bf16x8 __attribute__((ext_vector_type(8)));
typedef float f32x4 __attribute__((ext_vector_type(4)));
typedef unsigned int u32x4 __attribute__((ext_vector_type(4)));

#define QSCALE_LOG2E 0.18033688011112042f  // 0.125 * log2(e)

#define GLOAD_LDS16(gp, lp)                                                   \
  __builtin_amdgcn_global_load_lds(                                           \
      (const __attribute__((address_space(1))) unsigned int*)(const void*)(gp), \
      (__attribute__((address_space(3))) unsigned int*)(void*)(lp), 16, 0, 0)

__device__ __forceinline__ unsigned pack2(float lo, float hi) {
  union { __bf16 b; unsigned short u; } a, c;
  a.b = (__bf16)lo; c.b = (__bf16)hi;
  return (unsigned)a.u | ((unsigned)c.u << 16);
}

// fp32 -> bf16 bulk convert (x). 8 elems/thread.
__global__ __launch_bounds__(256) void cvt_k(const float* __restrict__ in,
                                             bf16* __restrict__ out) {
  const size_t i = ((size_t)blockIdx.x * 256 + threadIdx.x) * 8;
  float4 a = *(const float4*)(in + i);
  float4 b = *(const float4*)(in + i + 4);
  bf16x8 o = {(bf16)a.x, (bf16)a.y, (bf16)a.z, (bf16)a.w,
              (bf16)b.x, (bf16)b.y, (bf16)b.z, (bf16)b.w};
  *(bf16x8*)(out + i) = o;
}

// in fp32 [Kd][Nd] -> out bf16 [Nd][Kd] (transposed). 32x32 tiles.
__global__ __launch_bounds__(256) void transpose_k(const float* __restrict__ in,
                                                   bf16* __restrict__ out,
                                                   int Kd, int Nd) {
  __shared__ bf16 t[32][36];
  const int n0 = blockIdx.x * 32, k0 = blockIdx.y * 32;
  const int r = threadIdx.x >> 3, c4 = (threadIdx.x & 7) * 4;
  float4 v = *(const float4*)(in + (size_t)(k0 + r) * Nd + n0 + c4);
  t[c4 + 0][r] = (bf16)v.x; t[c4 + 1][r] = (bf16)v.y;
  t[c4 + 2][r] = (bf16)v.z; t[c4 + 3][r] = (bf16)v.w;
  __syncthreads();
  bf16x4 o = *(const bf16x4*)&t[r][c4];
  *(bf16x4*)(out + (size_t)(n0 + r) * Kd + k0 + c4) = o;
}

// C[M][N] = A[M][1024] @ Bt[N][1024]^T, both bf16. 128x128 tile, BK=32,
// global_load_lds width-16, linear LDS (m97 structure).
// QKV epilogue: n0<1024 -> Q (scaled) into qk; <2048 -> K into qk; else V^T into vt.
template <bool QKV>
__global__ __launch_bounds__(256) void gemm2(const bf16* __restrict__ A,
                                             const bf16* __restrict__ Bt,
                                             bf16* __restrict__ C,
                                             bf16* __restrict__ Vt) {
  __shared__ bf16 As[128][32];
  __shared__ bf16 Bs[128][32];
  const int tid = threadIdx.x;
  const int l = tid & 63, w = tid >> 6;
  const int g = l >> 4, q = l & 15;
  const int wm = w >> 1, wn = w & 1;
  const int m0 = blockIdx.x * 128, n0 = blockIdx.y * 128;
  const int lr = l >> 2, lc = (l & 3) * 8;

  f32x4 acc[4][4] = {};

  for (int k0 = 0; k0 < 1024; k0 += 32) {
    __syncthreads();
#pragma unroll
    for (int i = 0; i < 2; i++) {
      const int c = w + i * 4;
      GLOAD_LDS16(A + (size_t)(m0 + c * 16 + lr) * 1024 + k0 + lc, &As[c * 16][0]);
      GLOAD_LDS16(Bt + (size_t)(n0 + c * 16 + lr) * 1024 + k0 + lc, &Bs[c * 16][0]);
    }
    __syncthreads();

    bf16x8 af[4], bfr[4];
#pragma unroll
    for (int mi = 0; mi < 4; mi++)
      af[mi] = *(const bf16x8*)&As[wm * 64 + mi * 16 + q][g * 8];
#pragma unroll
    for (int ni = 0; ni < 4; ni++)
      bfr[ni] = *(const bf16x8*)&Bs[wn * 64 + ni * 16 + q][g * 8];
#pragma unroll
    for (int mi = 0; mi < 4; mi++)
#pragma unroll
      for (int ni = 0; ni < 4; ni++)
        acc[mi][ni] = __builtin_amdgcn_mfma_f32_16x16x32_bf16(af[mi], bfr[ni], acc[mi][ni], 0, 0, 0);
  }

  if (QKV && n0 >= 2048) {
    // V^T: vt[((b*16+h)*64+d)*2048 + n], 4 consecutive tokens per store.
#pragma unroll
    for (int mi = 0; mi < 4; mi++)
#pragma unroll
      for (int ni = 0; ni < 4; ni++) {
        const int vcol = n0 - 2048 + wn * 64 + ni * 16 + q;
        const int h = vcol >> 6, d = vcol & 63;
        const int t0 = m0 + wm * 64 + mi * 16 + g * 4;
        const int b = t0 >> 11, n = t0 & 2047;
        bf16x4 o = {(bf16)acc[mi][ni][0], (bf16)acc[mi][ni][1],
                    (bf16)acc[mi][ni][2], (bf16)acc[mi][ni][3]};
        *(bf16x4*)(Vt + ((size_t)(b * 16 + h) * 64 + d) * 2048 + n) = o;
      }
  } else {
    const int ldc = QKV ? 2048 : 1024;
    const float s = (QKV && n0 < 1024) ? QSCALE_LOG2E : 1.0f;
#pragma unroll
    for (int mi = 0; mi < 4; mi++)
#pragma unroll
      for (int ni = 0; ni < 4; ni++) {
        const int col = n0 + wn * 64 + ni * 16 + q;
#pragma unroll
        for (int r = 0; r < 4; r++) {
          const int row = m0 + wm * 64 + mi * 16 + g * 4 + r;
          C[(size_t)row * ldc + col] = (bf16)(acc[mi][ni][r] * s);
        }
      }
  }
}

// Flash attention. Grid (32 qtiles, 16 h, 4 b), 256 thr = 4 waves, 16 q-rows/wave.
// KVBLK=64. K and V^T tiles double-buffered in LDS via global_load_lds with
// XOR chunk swizzle (byte ^= (row&7)<<4) applied on the global SOURCE address
// (linear LDS dest) and on the ds_read side. Swapped S^T = mfma(K, Q); scores
// in log2 units (Q pre-scaled by 0.125*log2e), softmax via exp2.
__global__ __launch_bounds__(256) void attn_k(const bf16* __restrict__ qk,
                                              const bf16* __restrict__ vt,
                                              bf16* __restrict__ aout) {
  __shared__ bf16 Ks[2][64][64];   // [buf][kv][d]  (chunk-swizzled rows)
  __shared__ bf16 Vs[2][64][64];   // [buf][d][kv]  (chunk-swizzled rows)
  const int tid = threadIdx.x;
  const int l = tid & 63, w = tid >> 6;
  const int g = l >> 4, q = l & 15, q7 = q & 7;
  const int h = blockIdx.y, b = blockIdx.z;
  const int q0 = blockIdx.x * 64 + w * 16;

  const bf16* Kg = qk + (size_t)(b * 2048) * 2048 + 1024 + h * 64;
  const bf16* Vg = vt + ((size_t)(b * 16 + h) * 64) * 2048;

  // Q fragments (B operand of S^T): lane holds col q, k=d contiguous. Hoisted.
  bf16x8 qf[2];
  {
    const bf16* Qr = qk + (size_t)(b * 2048 + q0 + q) * 2048 + h * 64 + g * 8;
    qf[0] = *(const bf16x8*)Qr;
    qf[1] = *(const bf16x8*)(Qr + 32);
  }

  // Stage tile at kt into buf: 512 chunks of 16B each for K and V^T.
  // Dest is linear (chunk c at LDS offset c*16B); source chunk pre-swizzled.
  const int c0 = tid, c1 = 256 + tid;                 // this thread's chunks
  const int r0 = c0 >> 3, sp0 = ((c0 & 7) ^ (r0 & 7)) * 8;
  const int r1 = c1 >> 3, sp1 = ((c1 & 7) ^ (r1 & 7)) * 8;
  const int ub = (tid & 192) * 8;                     // wave-uniform dest elem base
#define STAGE_KV(buf, kt)                                                      \
  do {                                                                         \
    bf16* kd = &Ks[buf][0][0];                                                 \
    bf16* vd = &Vs[buf][0][0];                                                 \
    GLOAD_LDS16(Kg + (size_t)((kt) + r0) * 2048 + sp0, kd + ub);               \
    GLOAD_LDS16(Vg + (size_t)r0 * 2048 + (kt) + sp0, vd + ub);                 \
    GLOAD_LDS16(Kg + (size_t)((kt) + r1) * 2048 + sp1, kd + 2048 + ub);        \
    GLOAD_LDS16(Vg + (size_t)r1 * 2048 + (kt) + sp1, vd + 2048 + ub);          \
  } while (0)

  float m = -1e30f, lsum = 0.f;
  f32x4 oacc[4] = {};  // O^T: dchunk dc -> rows d = dc*16 + 4g + r, col q

  STAGE_KV(0, 0);
  __syncthreads();
  int cur = 0;

  for (int kt = 0; kt < 2048; kt += 64) {
    if (kt + 64 < 2048) STAGE_KV(cur ^ 1, kt + 64);

    const char* Kb = (const char*)&Ks[cur][0][0];
    const char* Vb = (const char*)&Vs[cur][0][0];
    const int cb = ((g ^ q7) << 4);                  // swizzled chunk byte offset

    // K fragments + S^T tiles: t -> kv 16t..16t+15.
    f32x4 st[4];
#pragma unroll
    for (int t = 0; t < 4; t++) {
      const int rb = (t * 16 + q) * 128;
      bf16x8 kf0 = *(const bf16x8*)(Kb + rb + cb);
      bf16x8 kf1 = *(const bf16x8*)(Kb + rb + (cb ^ 64));
      f32x4 z = {0.f, 0.f, 0.f, 0.f};
      z = __builtin_amdgcn_mfma_f32_16x16x32_bf16(kf0, qf[0], z, 0, 0, 0);
      st[t] = __builtin_amdgcn_mfma_f32_16x16x32_bf16(kf1, qf[1], z, 0, 0, 0);
    }
    // V^T fragments (issued before softmax so ds latency hides under VALU).
    bf16x8 vf[4][2];
#pragma unroll
    for (int dc = 0; dc < 4; dc++) {
      const int rb = (dc * 16 + q) * 128;
      vf[dc][0] = *(const bf16x8*)(Vb + rb + cb);
      vf[dc][1] = *(const bf16x8*)(Vb + rb + (cb ^ 64));
    }

    // Online softmax (log2 domain). Lane holds 16 scores of row q (kv=16t+4g+r).
    float tmax = st[0][0];
#pragma unroll
    for (int t = 0; t < 4; t++)
#pragma unroll
      for (int r = 0; r < 4; r++) tmax = fmaxf(tmax, st[t][r]);
    tmax = fmaxf(tmax, __shfl_xor(tmax, 16));
    tmax = fmaxf(tmax, __shfl_xor(tmax, 32));
    float corr = 1.0f;
    if (__ballot(tmax > m)) {  // defer-max: skip rescale when no row grew (exact)
      const float mnew = fmaxf(m, tmax);
      corr = exp2f(m - mnew);
      m = mnew;
#pragma unroll
      for (int dc = 0; dc < 4; dc++)
#pragma unroll
        for (int r = 0; r < 4; r++) oacc[dc][r] *= corr;
    }
    float p[4][4];
    float tsum = 0.f;
#pragma unroll
    for (int t = 0; t < 4; t++)
#pragma unroll
      for (int r = 0; r < 4; r++) { p[t][r] = exp2f(st[t][r] - m); tsum += p[t][r]; }
    tsum += __shfl_xor(tsum, 16);
    tsum += __shfl_xor(tsum, 32);
    lsum = lsum * corr + tsum;

    // Redistribute P^T into two PV B-fragments (kv 0..31 and 32..63 of this tile).
    unsigned pk[4][2];
#pragma unroll
    for (int t = 0; t < 4; t++) {
      pk[t][0] = pack2(p[t][0], p[t][1]);
      pk[t][1] = pack2(p[t][2], p[t][3]);
    }
    u32x4 bwA, bwB;
#pragma unroll
    for (int wd = 0; wd < 4; wd++) {
      const int src = q + 16 * ((g & 1) * 2 + (wd >> 1));
      const unsigned loA = (unsigned)__shfl((int)pk[0][wd & 1], src);
      const unsigned hiA = (unsigned)__shfl((int)pk[1][wd & 1], src);
      const unsigned loB = (unsigned)__shfl((int)pk[2][wd & 1], src);
      const unsigned hiB = (unsigned)__shfl((int)pk[3][wd & 1], src);
      bwA[wd] = (g < 2) ? loA : hiA;
      bwB[wd] = (g < 2) ? loB : hiB;
    }
    const bf16x8 pfA = __builtin_bit_cast(bf16x8, bwA);
    const bf16x8 pfB = __builtin_bit_cast(bf16x8, bwB);

#pragma unroll
    for (int dc = 0; dc < 4; dc++) {
      oacc[dc] = __builtin_amdgcn_mfma_f32_16x16x32_bf16(vf[dc][0], pfA, oacc[dc], 0, 0, 0);
      oacc[dc] = __builtin_amdgcn_mfma_f32_16x16x32_bf16(vf[dc][1], pfB, oacc[dc], 0, 0, 0);
    }

    __syncthreads();   // drains vmcnt (next tile staged) + protects LDS reuse
    cur ^= 1;
  }

  const float inv = 1.f / lsum;
  bf16* orow = aout + (size_t)(b * 2048 + q0 + q) * 1024 + h * 64;
#pragma unroll
  for (int dc = 0; dc < 4; dc++) {
    bf16x4 o = {(bf16)(oacc[dc][0] * inv), (bf16)(oacc[dc][1] * inv),
                (bf16)(oacc[dc][2] * inv), (bf16)(oacc[dc][3] * inv)};
    *(bf16x4*)(orow + dc * 16 + g * 4) = o;  // d = dc*16 + 4g + r
  }
#undef STAGE_KV
}

// Bias + LayerNorm epilogue: one block per row of proj[8192][1024].
__global__ __launch_bounds__(256) void ln_k(const bf16* __restrict__ proj,
                                            const float* __restrict__ bo,
                                            const float* __restrict__ gam,
                                            const float* __restrict__ bet,
                                            float* __restrict__ out) {
  const int row = blockIdx.x, tid = threadIdx.x;
  const int l = tid & 63, w = tid >> 6;
  bf16x4 pv = *(const bf16x4*)(proj + (size_t)row * 1024 + tid * 4);
  float4 bv = *(const float4*)(bo + tid * 4);
  float v0 = (float)pv[0] + bv.x, v1 = (float)pv[1] + bv.y;
  float v2 = (float)pv[2] + bv.z, v3 = (float)pv[3] + bv.w;
  float s = v0 + v1 + v2 + v3;
  float ss = v0 * v0 + v1 * v1 + v2 * v2 + v3 * v3;
#pragma unroll
  for (int off = 32; off > 0; off >>= 1) {
    s += __shfl_xor(s, off);
    ss += __shfl_xor(ss, off);
  }
  __shared__ float red[8];
  if (l == 0) { red[w] = s; red[w + 4] = ss; }
  __syncthreads();
  const float S = red[0] + red[1] + red[2] + red[3];
  const float SS = red[4] + red[5] + red[6] + red[7];
  const float mean = S * (1.f / 1024.f);
  const float var = SS * (1.f / 1024.f) - mean * mean;
  const float rs = rsqrtf(var + 1e-5f);
  float4 gv = *(const float4*)(gam + tid * 4);
  float4 btv = *(const float4*)(bet + tid * 4);
  float4 o;
  o.x = (v0 - mean) * rs * gv.x + btv.x;
  o.y = (v1 - mean) * rs * gv.y + btv.y;
  o.z = (v2 - mean) * rs * gv.z + btv.z;
  o.w = (v3 - mean) * rs * gv.w + btv.w;
  *(float4*)(out + (size_t)row * 1024 + tid * 4) = o;
}

extern "C" void kernel_launch(void* const* d_in, const int* in_sizes, int n_in,
                              void* d_out, int out_size, void* d_ws, size_t ws_size,
                              hipStream_t stream) {
  const float* x      = (const float*)d_in[0];
  const float* w_qkv  = (const float*)d_in[1];
  const float* w_out  = (const float*)d_in[2];
  const float* b_out  = (const float*)d_in[3];
  const float* gamma  = (const float*)d_in[4];
  const float* beta   = (const float*)d_in[5];
  float* out = (float*)d_out;

  char* ws = (char*)d_ws;
  bf16* xbf   = (bf16*)(ws);                      // 16,777,216 B (reused as aout)
  bf16* wqkvT = (bf16*)(ws + 16777216);           //  6,291,456 B
  bf16* woutT = (bf16*)(ws + 23068672);           //  2,097,152 B
  bf16* qkbuf = (bf16*)(ws + 25165824);           // 33,554,432 B
  bf16* vt    = (bf16*)(ws + 58720256);           // 16,777,216 B (reused as proj)
  bf16* aout  = xbf;
  bf16* proj  = vt;

  dim3 blk(256);
  cvt_k<<<4096, blk, 0, stream>>>(x, xbf);
  transpose_k<<<dim3(96, 32), blk, 0, stream>>>(w_qkv, wqkvT, 1024, 3072);
  transpose_k<<<dim3(32, 32), blk, 0, stream>>>(w_out, woutT, 1024, 1024);
  gemm2<true><<<dim3(64, 24), blk, 0, stream>>>(xbf, wqkvT, qkbuf, vt);
  attn_k<<<dim3(32, 16, 4), blk, 0, stream>>>(qkbuf, vt, aout);
  gemm2<false><<<dim3(64, 8), blk, 0, stream>>>(aout, woutT, proj, nullptr);
  ln_k<<<8192, blk, 0, stream>>>(proj, b_out, gamma, beta, out);
}

// Round 4
// 246.333 us; speedup vs baseline: 2.5101x; 1.1340x over previous
//
#include <hip/hip_runtime.h>

// Fused attention block: x @ Wqkv -> flash attention -> @ Wout + b -> LayerNorm
// B=4, N=2048, DIM=1024, HEADS=16, HEAD_DIM=64. fp32 in/out; bf16 MFMA inside.
//
// Workspace (75.5 MB):
//   xbf   bf16 [8192][1024]   (x converted; later reused as aout)
//   wqkvT bf16 [3072][1024]   (w_qkv^T)
//   woutT bf16 [1024][1024]   (w_out^T)
//   qk    bf16 [8192][2048]   (Q cols 0..1023 pre-scaled by 0.125, K cols 1024..2047)
//   vt    bf16 [4][16][64][2048] (V^T per (b,h); later reused as proj)

typedef __bf16 bf16;
typedef __bf16 bf16x4 __attribute__((ext_vector_type(4)));
typedef __bf16 bf16x8 __attribute__((ext_vector_type(8)));
typedef float f32x4 __attribute__((ext_vector_type(4)));
typedef unsigned int u32x4 __attribute__((ext_vector_type(4)));

#define QSCALE 0.125f

#define GLOAD_LDS16(gp, lp)                                                   \
  __builtin_amdgcn_global_load_lds(                                           \
      (const __attribute__((address_space(1))) unsigned int*)(const void*)(gp), \
      (__attribute__((address_space(3))) unsigned int*)(void*)(lp), 16, 0, 0)

__device__ __forceinline__ unsigned pack2(float lo, float hi) {
  union { __bf16 b; unsigned short u; } a, c;
  a.b = (__bf16)lo; c.b = (__bf16)hi;
  return (unsigned)a.u | ((unsigned)c.u << 16);
}

// fp32 -> bf16 bulk convert (x). 8 elems/thread.
__global__ __launch_bounds__(256) void cvt_k(const float* __restrict__ in,
                                             bf16* __restrict__ out) {
  const size_t i = ((size_t)blockIdx.x * 256 + threadIdx.x) * 8;
  float4 a = *(const float4*)(in + i);
  float4 b = *(const float4*)(in + i + 4);
  bf16x8 o = {(bf16)a.x, (bf16)a.y, (bf16)a.z, (bf16)a.w,
              (bf16)b.x, (bf16)b.y, (bf16)b.z, (bf16)b.w};
  *(bf16x8*)(out + i) = o;
}

// in fp32 [Kd][Nd] -> out bf16 [Nd][Kd] (transposed). 32x32 tiles.
__global__ __launch_bounds__(256) void transpose_k(const float* __restrict__ in,
                                                   bf16* __restrict__ out,
                                                   int Kd, int Nd) {
  __shared__ bf16 t[32][36];
  const int n0 = blockIdx.x * 32, k0 = blockIdx.y * 32;
  const int r = threadIdx.x >> 3, c4 = (threadIdx.x & 7) * 4;
  float4 v = *(const float4*)(in + (size_t)(k0 + r) * Nd + n0 + c4);
  t[c4 + 0][r] = (bf16)v.x; t[c4 + 1][r] = (bf16)v.y;
  t[c4 + 2][r] = (bf16)v.z; t[c4 + 3][r] = (bf16)v.w;
  __syncthreads();
  bf16x4 o = *(const bf16x4*)&t[r][c4];
  *(bf16x4*)(out + (size_t)(n0 + r) * Kd + k0 + c4) = o;
}

// C[M][N] = A[M][1024] @ Bt[N][1024]^T, both bf16. 128x128 tile, BK=32,
// global_load_lds width-16, linear LDS (m97 structure).
// QKV epilogue: n0<1024 -> Q (scaled) into qk; <2048 -> K into qk; else V^T into vt.
template <bool QKV>
__global__ __launch_bounds__(256) void gemm2(const bf16* __restrict__ A,
                                             const bf16* __restrict__ Bt,
                                             bf16* __restrict__ C,
                                             bf16* __restrict__ Vt) {
  __shared__ bf16 As[128][32];
  __shared__ bf16 Bs[128][32];
  const int tid = threadIdx.x;
  const int l = tid & 63, w = tid >> 6;
  const int g = l >> 4, q = l & 15;
  const int wm = w >> 1, wn = w & 1;
  const int m0 = blockIdx.x * 128, n0 = blockIdx.y * 128;
  const int lr = l >> 2, lc = (l & 3) * 8;

  f32x4 acc[4][4] = {};

  for (int k0 = 0; k0 < 1024; k0 += 32) {
    __syncthreads();
#pragma unroll
    for (int i = 0; i < 2; i++) {
      const int c = w + i * 4;
      GLOAD_LDS16(A + (size_t)(m0 + c * 16 + lr) * 1024 + k0 + lc, &As[c * 16][0]);
      GLOAD_LDS16(Bt + (size_t)(n0 + c * 16 + lr) * 1024 + k0 + lc, &Bs[c * 16][0]);
    }
    __syncthreads();

    bf16x8 af[4], bfr[4];
#pragma unroll
    for (int mi = 0; mi < 4; mi++)
      af[mi] = *(const bf16x8*)&As[wm * 64 + mi * 16 + q][g * 8];
#pragma unroll
    for (int ni = 0; ni < 4; ni++)
      bfr[ni] = *(const bf16x8*)&Bs[wn * 64 + ni * 16 + q][g * 8];
#pragma unroll
    for (int mi = 0; mi < 4; mi++)
#pragma unroll
      for (int ni = 0; ni < 4; ni++)
        acc[mi][ni] = __builtin_amdgcn_mfma_f32_16x16x32_bf16(af[mi], bfr[ni], acc[mi][ni], 0, 0, 0);
  }

  if (QKV && n0 >= 2048) {
    // V^T: vt[((b*16+h)*64+d)*2048 + n], 4 consecutive tokens per store.
#pragma unroll
    for (int mi = 0; mi < 4; mi++)
#pragma unroll
      for (int ni = 0; ni < 4; ni++) {
        const int vcol = n0 - 2048 + wn * 64 + ni * 16 + q;
        const int h = vcol >> 6, d = vcol & 63;
        const int t0 = m0 + wm * 64 + mi * 16 + g * 4;
        const int b = t0 >> 11, n = t0 & 2047;
        bf16x4 o = {(bf16)acc[mi][ni][0], (bf16)acc[mi][ni][1],
                    (bf16)acc[mi][ni][2], (bf16)acc[mi][ni][3]};
        *(bf16x4*)(Vt + ((size_t)(b * 16 + h) * 64 + d) * 2048 + n) = o;
      }
  } else {
    const int ldc = QKV ? 2048 : 1024;
    const float s = (QKV && n0 < 1024) ? QSCALE : 1.0f;
#pragma unroll
    for (int mi = 0; mi < 4; mi++)
#pragma unroll
      for (int ni = 0; ni < 4; ni++) {
        const int col = n0 + wn * 64 + ni * 16 + q;
#pragma unroll
        for (int r = 0; r < 4; r++) {
          const int row = m0 + wm * 64 + mi * 16 + g * 4 + r;
          C[(size_t)row * ldc + col] = (bf16)(acc[mi][ni][r] * s);
        }
      }
  }
}

// Flash attention. Grid (16 qtiles, 16 h, 4 b), 512 thr = 8 waves, 16 q-rows/wave.
// KVBLK=64; K and V^T tiles double-buffered in LDS (shared by all 8 waves),
// staged via global_load_lds with XOR chunk swizzle (byte ^= (row&7)<<4) applied
// on the global SOURCE address (linear LDS dest) and on the ds_read side.
// Swapped S^T = mfma(K, Q); softmax via fast __expf.
__global__ __launch_bounds__(512) void attn_k(const bf16* __restrict__ qk,
                                              const bf16* __restrict__ vt,
                                              bf16* __restrict__ aout) {
  __shared__ bf16 Ks[2][64][64];   // [buf][kv][d]  (chunk-swizzled rows)
  __shared__ bf16 Vs[2][64][64];   // [buf][d][kv]  (chunk-swizzled rows)
  const int tid = threadIdx.x;
  const int l = tid & 63, w = tid >> 6;
  const int g = l >> 4, q = l & 15, q7 = q & 7;
  const int h = blockIdx.y, b = blockIdx.z;
  const int q0 = blockIdx.x * 128 + w * 16;

  const bf16* Kg = qk + (size_t)(b * 2048) * 2048 + 1024 + h * 64;
  const bf16* Vg = vt + ((size_t)(b * 16 + h) * 64) * 2048;

  // Q fragments (B operand of S^T): lane holds col q, k=d contiguous. Hoisted.
  bf16x8 qf[2];
  {
    const bf16* Qr = qk + (size_t)(b * 2048 + q0 + q) * 2048 + h * 64 + g * 8;
    qf[0] = *(const bf16x8*)Qr;
    qf[1] = *(const bf16x8*)(Qr + 32);
  }

  // Stage: 512 chunks of 16B per tile; thread tid stages K chunk tid + V chunk tid.
  // Dest linear (chunk c at byte c*16); source column pre-swizzled.
  const int r0 = tid >> 3, sp0 = ((tid & 7) ^ (r0 & 7)) * 8;
  const int ub = (tid >> 6) << 9;                     // wave-uniform dest elem base
#define STAGE_KV(buf, kt)                                                      \
  do {                                                                         \
    GLOAD_LDS16(Kg + (size_t)((kt) + r0) * 2048 + sp0, &Ks[buf][0][0] + ub);   \
    GLOAD_LDS16(Vg + (size_t)r0 * 2048 + (kt) + sp0, &Vs[buf][0][0] + ub);     \
  } while (0)

  float m = -1e30f, lsum = 0.f;
  f32x4 oacc[4] = {};  // O^T: dchunk dc -> rows d = dc*16 + 4g + r, col q

  STAGE_KV(0, 0);
  __syncthreads();
  int cur = 0;

  for (int kt = 0; kt < 2048; kt += 64) {
    if (kt + 64 < 2048) STAGE_KV(cur ^ 1, kt + 64);

    const char* Kb = (const char*)&Ks[cur][0][0];
    const char* Vb = (const char*)&Vs[cur][0][0];
    const int cb = ((g ^ q7) << 4);                  // swizzled chunk byte offset

    // K fragments + S^T tiles: t -> kv 16t..16t+15.
    f32x4 st[4];
    __builtin_amdgcn_s_setprio(1);
#pragma unroll
    for (int t = 0; t < 4; t++) {
      const int rb = (t * 16 + q) * 128;
      bf16x8 kf0 = *(const bf16x8*)(Kb + rb + cb);
      bf16x8 kf1 = *(const bf16x8*)(Kb + rb + (cb ^ 64));
      f32x4 z = {0.f, 0.f, 0.f, 0.f};
      z = __builtin_amdgcn_mfma_f32_16x16x32_bf16(kf0, qf[0], z, 0, 0, 0);
      st[t] = __builtin_amdgcn_mfma_f32_16x16x32_bf16(kf1, qf[1], z, 0, 0, 0);
    }
    __builtin_amdgcn_s_setprio(0);
    // V^T fragments (issued before softmax so ds latency hides under VALU).
    bf16x8 vf[4][2];
#pragma unroll
    for (int dc = 0; dc < 4; dc++) {
      const int rb = (dc * 16 + q) * 128;
      vf[dc][0] = *(const bf16x8*)(Vb + rb + cb);
      vf[dc][1] = *(const bf16x8*)(Vb + rb + (cb ^ 64));
    }

    // Online softmax. Lane holds 16 scores of row q (kv=16t+4g+r).
    float tmax = st[0][0];
#pragma unroll
    for (int t = 0; t < 4; t++)
#pragma unroll
      for (int r = 0; r < 4; r++) tmax = fmaxf(tmax, st[t][r]);
    tmax = fmaxf(tmax, __shfl_xor(tmax, 16));
    tmax = fmaxf(tmax, __shfl_xor(tmax, 32));
    float corr = 1.0f;
    if (__ballot(tmax > m)) {  // defer-max: skip rescale when no row grew (exact)
      const float mnew = fmaxf(m, tmax);
      corr = __expf(m - mnew);
      m = mnew;
#pragma unroll
      for (int dc = 0; dc < 4; dc++)
#pragma unroll
        for (int r = 0; r < 4; r++) oacc[dc][r] *= corr;
    }
    float p[4][4];
    float tsum = 0.f;
#pragma unroll
    for (int t = 0; t < 4; t++)
#pragma unroll
      for (int r = 0; r < 4; r++) { p[t][r] = __expf(st[t][r] - m); tsum += p[t][r]; }
    tsum += __shfl_xor(tsum, 16);
    tsum += __shfl_xor(tsum, 32);
    lsum = lsum * corr + tsum;

    // Redistribute P^T into two PV B-fragments (kv 0..31 and 32..63 of this tile).
    unsigned pk[4][2];
#pragma unroll
    for (int t = 0; t < 4; t++) {
      pk[t][0] = pack2(p[t][0], p[t][1]);
      pk[t][1] = pack2(p[t][2], p[t][3]);
    }
    u32x4 bwA, bwB;
#pragma unroll
    for (int wd = 0; wd < 4; wd++) {
      const int src = q + 16 * ((g & 1) * 2 + (wd >> 1));
      const unsigned loA = (unsigned)__shfl((int)pk[0][wd & 1], src);
      const unsigned hiA = (unsigned)__shfl((int)pk[1][wd & 1], src);
      const unsigned loB = (unsigned)__shfl((int)pk[2][wd & 1], src);
      const unsigned hiB = (unsigned)__shfl((int)pk[3][wd & 1], src);
      bwA[wd] = (g < 2) ? loA : hiA;
      bwB[wd] = (g < 2) ? loB : hiB;
    }
    const bf16x8 pfA = __builtin_bit_cast(bf16x8, bwA);
    const bf16x8 pfB = __builtin_bit_cast(bf16x8, bwB);

    __builtin_amdgcn_s_setprio(1);
#pragma unroll
    for (int dc = 0; dc < 4; dc++) {
      oacc[dc] = __builtin_amdgcn_mfma_f32_16x16x32_bf16(vf[dc][0], pfA, oacc[dc], 0, 0, 0);
      oacc[dc] = __builtin_amdgcn_mfma_f32_16x16x32_bf16(vf[dc][1], pfB, oacc[dc], 0, 0, 0);
    }
    __builtin_amdgcn_s_setprio(0);

    __syncthreads();   // drains vmcnt (next tile staged) + protects LDS reuse
    cur ^= 1;
  }

  const float inv = 1.f / lsum;
  bf16* orow = aout + (size_t)(b * 2048 + q0 + q) * 1024 + h * 64;
#pragma unroll
  for (int dc = 0; dc < 4; dc++) {
    bf16x4 o = {(bf16)(oacc[dc][0] * inv), (bf16)(oacc[dc][1] * inv),
                (bf16)(oacc[dc][2] * inv), (bf16)(oacc[dc][3] * inv)};
    *(bf16x4*)(orow + dc * 16 + g * 4) = o;  // d = dc*16 + 4g + r
  }
#undef STAGE_KV
}

// Bias + LayerNorm epilogue: one block per row of proj[8192][1024].
__global__ __launch_bounds__(256) void ln_k(const bf16* __restrict__ proj,
                                            const float* __restrict__ bo,
                                            const float* __restrict__ gam,
                                            const float* __restrict__ bet,
                                            float* __restrict__ out) {
  const int row = blockIdx.x, tid = threadIdx.x;
  const int l = tid & 63, w = tid >> 6;
  bf16x4 pv = *(const bf16x4*)(proj + (size_t)row * 1024 + tid * 4);
  float4 bv = *(const float4*)(bo + tid * 4);
  float v0 = (float)pv[0] + bv.x, v1 = (float)pv[1] + bv.y;
  float v2 = (float)pv[2] + bv.z, v3 = (float)pv[3] + bv.w;
  float s = v0 + v1 + v2 + v3;
  float ss = v0 * v0 + v1 * v1 + v2 * v2 + v3 * v3;
#pragma unroll
  for (int off = 32; off > 0; off >>= 1) {
    s += __shfl_xor(s, off);
    ss += __shfl_xor(ss, off);
  }
  __shared__ float red[8];
  if (l == 0) { red[w] = s; red[w + 4] = ss; }
  __syncthreads();
  const float S = red[0] + red[1] + red[2] + red[3];
  const float SS = red[4] + red[5] + red[6] + red[7];
  const float mean = S * (1.f / 1024.f);
  const float var = SS * (1.f / 1024.f) - mean * mean;
  const float rs = rsqrtf(var + 1e-5f);
  float4 gv = *(const float4*)(gam + tid * 4);
  float4 btv = *(const float4*)(bet + tid * 4);
  float4 o;
  o.x = (v0 - mean) * rs * gv.x + btv.x;
  o.y = (v1 - mean) * rs * gv.y + btv.y;
  o.z = (v2 - mean) * rs * gv.z + btv.z;
  o.w = (v3 - mean) * rs * gv.w + btv.w;
  *(float4*)(out + (size_t)row * 1024 + tid * 4) = o;
}

extern "C" void kernel_launch(void* const* d_in, const int* in_sizes, int n_in,
                              void* d_out, int out_size, void* d_ws, size_t ws_size,
                              hipStream_t stream) {
  const float* x      = (const float*)d_in[0];
  const float* w_qkv  = (const float*)d_in[1];
  const float* w_out  = (const float*)d_in[2];
  const float* b_out  = (const float*)d_in[3];
  const float* gamma  = (const float*)d_in[4];
  const float* beta   = (const float*)d_in[5];
  float* out = (float*)d_out;

  char* ws = (char*)d_ws;
  bf16* xbf   = (bf16*)(ws);                      // 16,777,216 B (reused as aout)
  bf16* wqkvT = (bf16*)(ws + 16777216);           //  6,291,456 B
  bf16* woutT = (bf16*)(ws + 23068672);           //  2,097,152 B
  bf16* qkbuf = (bf16*)(ws + 25165824);           // 33,554,432 B
  bf16* vt    = (bf16*)(ws + 58720256);           // 16,777,216 B (reused as proj)
  bf16* aout  = xbf;
  bf16* proj  = vt;

  dim3 blk(256);
  cvt_k<<<4096, blk, 0, stream>>>(x, xbf);
  transpose_k<<<dim3(96, 32), blk, 0, stream>>>(w_qkv, wqkvT, 1024, 3072);
  transpose_k<<<dim3(32, 32), blk, 0, stream>>>(w_out, woutT, 1024, 1024);
  gemm2<true><<<dim3(64, 24), blk, 0, stream>>>(xbf, wqkvT, qkbuf, vt);
  attn_k<<<dim3(16, 16, 4), dim3(512), 0, stream>>>(qkbuf, vt, aout);
  gemm2<false><<<dim3(64, 8), blk, 0, stream>>>(aout, woutT, proj, nullptr);
  ln_k<<<8192, blk, 0, stream>>>(proj, b_out, gamma, beta, out);
}